// Round 9
// baseline (152.859 us; speedup 1.0000x reference)
//
#include <hip/hip_runtime.h>
#include <math.h>

#define LSEQ 2048
#define HDIM 1024
#define BATCH 4
#define ROWS (BATCH * LSEQ)   // 8192
#define NBAND 9               // |i-j| <= 4

typedef __attribute__((ext_vector_type(8))) short bf16x8;
typedef __attribute__((ext_vector_type(4))) float f32x4;
typedef __attribute__((ext_vector_type(8))) unsigned short u16x8;

#define AS3 __attribute__((address_space(3)))
#define AS1 __attribute__((address_space(1)))

__device__ __forceinline__ void gload16(const void* gp, void* lp) {
    __builtin_amdgcn_global_load_lds((AS1 const unsigned*)gp, (AS3 unsigned*)lp, 16, 0, 0);
}

__device__ __forceinline__ unsigned short f2bf(float x) {
    unsigned u = __float_as_uint(x);
    u += 0x7FFFu + ((u >> 16) & 1u);
    return (unsigned short)(u >> 16);
}
__device__ __forceinline__ float bf2f(unsigned short h) {
    return __uint_as_float(((unsigned)h) << 16);
}

// split 8 fp32 (two float4) into bf16 hi/lo fragments
__device__ __forceinline__ void split8(float4 a, float4 b, bf16x8& hi, bf16x8& lo) {
    float v[8] = {a.x, a.y, a.z, a.w, b.x, b.y, b.z, b.w};
#pragma unroll
    for (int j = 0; j < 8; j++) {
        unsigned short h = f2bf(v[j]);
        hi[j] = (short)h;
        lo[j] = (short)f2bf(v[j] - bf2f(h));
    }
}

// ---------------------------------------------------------------------------
// w partial: wpart[blk][c] = sum_{h in blk range} Wk[h,c] * bq[h] (64 blocks)
// ---------------------------------------------------------------------------
__global__ __launch_bounds__(256) void wpart_kernel(const float* __restrict__ Wk,
                                                    const float* __restrict__ bq,
                                                    float* __restrict__ wpart) {
    const int b = blockIdx.x;
    const int c0 = threadIdx.x * 4;
    float4 acc = {0.f, 0.f, 0.f, 0.f};
#pragma unroll
    for (int hh = 0; hh < 16; hh++) {
        const int h = b * 16 + hh;
        const float s = bq[h];
        float4 v = *reinterpret_cast<const float4*>(&Wk[(size_t)h * HDIM + c0]);
        acc.x += v.x * s; acc.y += v.y * s; acc.z += v.z * s; acc.w += v.w * s;
    }
    *reinterpret_cast<float4*>(&wpart[(size_t)b * HDIM + c0]) = acc;
}

__global__ __launch_bounds__(256) void wreduce(const float* __restrict__ wpart,
                                               float* __restrict__ w) {
    const int c = blockIdx.x * 256 + threadIdx.x;
    float s = 0.f;
#pragma unroll
    for (int b = 0; b < 64; b++) s += wpart[(size_t)b * HDIM + c];
    w[c] = s;
}

// ---------------------------------------------------------------------------
// Transposed split-convert: dst[n,h] = split(src[h,n]); z=0 -> Wq, z=1 -> Wk
// ---------------------------------------------------------------------------
__global__ __launch_bounds__(256) void transpose_convert(const float* __restrict__ Wq,
                                                         const float* __restrict__ Wk,
                                                         unsigned short* __restrict__ qhi,
                                                         unsigned short* __restrict__ qlo,
                                                         unsigned short* __restrict__ khi,
                                                         unsigned short* __restrict__ klo) {
    __shared__ float tile[64][65];
    const int z = blockIdx.z;
    const float* src = z ? Wk : Wq;
    unsigned short* dh = z ? khi : qhi;
    unsigned short* dl = z ? klo : qlo;
    const int n0 = blockIdx.x * 64;
    const int h0 = blockIdx.y * 64;
    const int tid = threadIdx.x;

#pragma unroll
    for (int p = 0; p < 4; p++) {
        const int h = p * 16 + (tid >> 4);
        const int n = (tid & 15) * 4;
        float4 v = *reinterpret_cast<const float4*>(&src[(size_t)(h0 + h) * HDIM + n0 + n]);
        tile[h][n + 0] = v.x; tile[h][n + 1] = v.y; tile[h][n + 2] = v.z; tile[h][n + 3] = v.w;
    }
    __syncthreads();
#pragma unroll
    for (int p = 0; p < 2; p++) {
        const int n = p * 32 + (tid >> 3);
        const int h = (tid & 7) * 8;
        u16x8 hv, lv;
#pragma unroll
        for (int j = 0; j < 8; j++) {
            float x = tile[h + j][n];
            unsigned short hb = f2bf(x);
            hv[j] = hb;
            lv[j] = f2bf(x - bf2f(hb));
        }
        *reinterpret_cast<u16x8*>(&dh[(size_t)(n0 + n) * HDIM + h0 + h]) = hv;
        *reinterpret_cast<u16x8*>(&dl[(size_t)(n0 + n) * HDIM + h0 + h]) = lv;
    }
}

// ---------------------------------------------------------------------------
// Fused: split-convert k rows to bf16 hi/lo AND beta[r] = k_r . w
// ---------------------------------------------------------------------------
__global__ __launch_bounds__(256) void convert_k_beta(const float* __restrict__ k,
                                                      const float* __restrict__ w,
                                                      unsigned short* __restrict__ Xhi,
                                                      unsigned short* __restrict__ Xlo,
                                                      float* __restrict__ beta) {
    __shared__ float red[4];
    const int r = blockIdx.x;
    const int t = threadIdx.x;
    float4 v = *reinterpret_cast<const float4*>(&k[(size_t)r * HDIM + t * 4]);
    float4 wv = *reinterpret_cast<const float4*>(&w[t * 4]);
    ushort4 h, l;
    h.x = f2bf(v.x); l.x = f2bf(v.x - bf2f(h.x));
    h.y = f2bf(v.y); l.y = f2bf(v.y - bf2f(h.y));
    h.z = f2bf(v.z); l.z = f2bf(v.z - bf2f(h.z));
    h.w = f2bf(v.w); l.w = f2bf(v.w - bf2f(h.w));
    reinterpret_cast<ushort4*>(Xhi)[(size_t)r * 256 + t] = h;
    reinterpret_cast<ushort4*>(Xlo)[(size_t)r * 256 + t] = l;
    float d = v.x * wv.x + v.y * wv.y + v.z * wv.z + v.w * wv.w;
#pragma unroll
    for (int off = 32; off > 0; off >>= 1) d += __shfl_xor(d, off, 64);
    if ((t & 63) == 0) red[t >> 6] = d;
    __syncthreads();
    if (t == 0) beta[r] = red[0] + red[1] + red[2] + red[3];
}

// ---------------------------------------------------------------------------
// Split-K GEMM for M = WqT @ WkT^T: grid (8,8,8). (128^2 tile, 4 waves)
// ---------------------------------------------------------------------------
__global__ __launch_bounds__(256, 2) void gemm_part(
        const unsigned short* __restrict__ Ahi, const unsigned short* __restrict__ Alo,
        const unsigned short* __restrict__ Bhi, const unsigned short* __restrict__ Blo,
        float* __restrict__ Cparts) {
    __shared__ unsigned short sh[4 * 4096];
    const int AHI = 0, ALO = 4096, BHI = 8192, BLO = 12288;
    const int tid = threadIdx.x;
    const int w = tid >> 6, l = tid & 63;
    const int wr = w >> 1, wc = w & 1;
    const int row0 = blockIdx.x * 128, col0 = blockIdx.y * 128;
    const int kbeg = blockIdx.z * 128;
    float* C = Cparts + (size_t)blockIdx.z * HDIM * HDIM;
    const int srow0 = (l >> 2), scbp = l & 3;

    f32x4 acc[4][4];
#pragma unroll
    for (int m = 0; m < 4; m++)
#pragma unroll
        for (int n = 0; n < 4; n++) acc[m][n] = (f32x4){0.f, 0.f, 0.f, 0.f};

    const int fr_a[4] = {wr * 64 + (l & 15), wr * 64 + 16 + (l & 15),
                         wr * 64 + 32 + (l & 15), wr * 64 + 48 + (l & 15)};
    const int fr_b[4] = {wc * 64 + (l & 15), wc * 64 + 16 + (l & 15),
                         wc * 64 + 32 + (l & 15), wc * 64 + 48 + (l & 15)};
    const int cb = l >> 4;

    for (int k0 = kbeg; k0 < kbeg + 128; k0 += 32) {
#pragma unroll
        for (int i = 0; i < 2; i++) {
            const int seg = i * 4 + w;
            const int row = seg * 16 + srow0;
            const int cbs = scbp ^ ((row >> 1) & 3);
            gload16(Ahi + (size_t)(row0 + row) * HDIM + k0 + cbs * 8, &sh[AHI + seg * 512]);
            gload16(Alo + (size_t)(row0 + row) * HDIM + k0 + cbs * 8, &sh[ALO + seg * 512]);
            gload16(Bhi + (size_t)(col0 + row) * HDIM + k0 + cbs * 8, &sh[BHI + seg * 512]);
            gload16(Blo + (size_t)(col0 + row) * HDIM + k0 + cbs * 8, &sh[BLO + seg * 512]);
        }
        __syncthreads();

        bf16x8 ah[4], al[4], bh[4], bl[4];
#pragma unroll
        for (int m = 0; m < 4; m++) {
            const int r = fr_a[m];
            const int cbs = cb ^ ((r >> 1) & 3);
            ah[m] = *reinterpret_cast<const bf16x8*>(&sh[AHI + r * 32 + cbs * 8]);
            al[m] = *reinterpret_cast<const bf16x8*>(&sh[ALO + r * 32 + cbs * 8]);
        }
#pragma unroll
        for (int n = 0; n < 4; n++) {
            const int r = fr_b[n];
            const int cbs = cb ^ ((r >> 1) & 3);
            bh[n] = *reinterpret_cast<const bf16x8*>(&sh[BHI + r * 32 + cbs * 8]);
            bl[n] = *reinterpret_cast<const bf16x8*>(&sh[BLO + r * 32 + cbs * 8]);
        }
#pragma unroll
        for (int m = 0; m < 4; m++)
#pragma unroll
            for (int n = 0; n < 4; n++) {
                acc[m][n] = __builtin_amdgcn_mfma_f32_16x16x32_bf16(ah[m], bh[n], acc[m][n], 0, 0, 0);
                acc[m][n] = __builtin_amdgcn_mfma_f32_16x16x32_bf16(ah[m], bl[n], acc[m][n], 0, 0, 0);
                acc[m][n] = __builtin_amdgcn_mfma_f32_16x16x32_bf16(al[m], bh[n], acc[m][n], 0, 0, 0);
            }
        __syncthreads();
    }

    const int lcol = l & 15, lrow = (l >> 4) * 4;
#pragma unroll
    for (int n = 0; n < 4; n++) {
        const int colg = col0 + wc * 64 + n * 16 + lcol;
#pragma unroll
        for (int m = 0; m < 4; m++) {
            const int rowg = row0 + wr * 64 + m * 16 + lrow;
#pragma unroll
            for (int v = 0; v < 4; v++)
                C[(size_t)(rowg + v) * HDIM + colg] = acc[m][n][v];
        }
    }
}

// ---------------------------------------------------------------------------
// Reduce 8 M-parts and split-convert to bf16 hi/lo.
// ---------------------------------------------------------------------------
__global__ __launch_bounds__(256) void reduceM_convert(const float* __restrict__ Mparts,
                                                       unsigned short* __restrict__ Mhi,
                                                       unsigned short* __restrict__ Mlo) {
    const int idx4 = blockIdx.x * 256 + threadIdx.x;
    float4 s = {0.f, 0.f, 0.f, 0.f};
#pragma unroll
    for (int z = 0; z < 8; z++) {
        float4 v = reinterpret_cast<const float4*>(Mparts + (size_t)z * HDIM * HDIM)[idx4];
        s.x += v.x; s.y += v.y; s.z += v.z; s.w += v.w;
    }
    ushort4 h, l;
    h.x = f2bf(s.x); l.x = f2bf(s.x - bf2f(h.x));
    h.y = f2bf(s.y); l.y = f2bf(s.y - bf2f(h.y));
    h.z = f2bf(s.z); l.z = f2bf(s.z - bf2f(h.z));
    h.w = f2bf(s.w); l.w = f2bf(s.w - bf2f(h.w));
    reinterpret_cast<ushort4*>(Mhi)[idx4] = h;
    reinterpret_cast<ushort4*>(Mlo)[idx4] = l;
}

// ---------------------------------------------------------------------------
// Big GEMM (t = K @ M^T), 256x128 tile, BK=32, 512 threads = 8 waves (4x2).
// Each wave owns a 64x64 output (4x4 fragments, 3-term bf16 split).
// LDS 48KB: Ahi 16KB + Alo 16KB + Bhi 8KB + Blo 8KB, same swizzle involution
// as the verified 128^2 kernel (cb ^= (row>>1)&3 on both sides).
// Grid (32, 8) = 256 blocks = 1/CU x 8 waves.
// ---------------------------------------------------------------------------
__global__ __launch_bounds__(512, 2) void gemm_t2(
        const unsigned short* __restrict__ Ahi, const unsigned short* __restrict__ Alo,
        const unsigned short* __restrict__ Bhi, const unsigned short* __restrict__ Blo,
        float* __restrict__ C) {
    __shared__ unsigned short sh[24576];   // 48 KB
    const int AHI = 0, ALO = 8192, BHI = 16384, BLO = 20480;
    const int tid = threadIdx.x;
    const int w = tid >> 6, l = tid & 63;          // 8 waves
    const int wr = w >> 1, wc = w & 1;             // 4 x 2 wave grid
    const int row0 = blockIdx.x * 256, col0 = blockIdx.y * 128;
    const int srow0 = (l >> 2), scbp = l & 3;

    f32x4 acc[4][4];
#pragma unroll
    for (int m = 0; m < 4; m++)
#pragma unroll
        for (int n = 0; n < 4; n++) acc[m][n] = (f32x4){0.f, 0.f, 0.f, 0.f};

    const int fr_a[4] = {wr * 64 + (l & 15), wr * 64 + 16 + (l & 15),
                         wr * 64 + 32 + (l & 15), wr * 64 + 48 + (l & 15)};
    const int fr_b[4] = {wc * 64 + (l & 15), wc * 64 + 16 + (l & 15),
                         wc * 64 + 32 + (l & 15), wc * 64 + 48 + (l & 15)};
    const int cb = l >> 4;

    for (int k0 = 0; k0 < HDIM; k0 += 32) {
        // ---- stage: A 16 segs (2/wave), B 8 segs (1/wave); 6 gload16/thread
#pragma unroll
        for (int i = 0; i < 2; i++) {
            const int seg = i * 8 + w;                     // 0..15
            const int row = seg * 16 + srow0;              // 0..255
            const int cbs = scbp ^ ((row >> 1) & 3);
            gload16(Ahi + (size_t)(row0 + row) * HDIM + k0 + cbs * 8, &sh[AHI + seg * 512]);
            gload16(Alo + (size_t)(row0 + row) * HDIM + k0 + cbs * 8, &sh[ALO + seg * 512]);
        }
        {
            const int seg = w;                             // 0..7
            const int row = seg * 16 + srow0;              // 0..127
            const int cbs = scbp ^ ((row >> 1) & 3);
            gload16(Bhi + (size_t)(col0 + row) * HDIM + k0 + cbs * 8, &sh[BHI + seg * 512]);
            gload16(Blo + (size_t)(col0 + row) * HDIM + k0 + cbs * 8, &sh[BLO + seg * 512]);
        }
        __syncthreads();

        bf16x8 ah[4], al[4], bh[4], bl[4];
#pragma unroll
        for (int m = 0; m < 4; m++) {
            const int r = fr_a[m];
            const int cbs = cb ^ ((r >> 1) & 3);
            ah[m] = *reinterpret_cast<const bf16x8*>(&sh[AHI + r * 32 + cbs * 8]);
            al[m] = *reinterpret_cast<const bf16x8*>(&sh[ALO + r * 32 + cbs * 8]);
        }
#pragma unroll
        for (int n = 0; n < 4; n++) {
            const int r = fr_b[n];
            const int cbs = cb ^ ((r >> 1) & 3);
            bh[n] = *reinterpret_cast<const bf16x8*>(&sh[BHI + r * 32 + cbs * 8]);
            bl[n] = *reinterpret_cast<const bf16x8*>(&sh[BLO + r * 32 + cbs * 8]);
        }
#pragma unroll
        for (int m = 0; m < 4; m++)
#pragma unroll
            for (int n = 0; n < 4; n++) {
                acc[m][n] = __builtin_amdgcn_mfma_f32_16x16x32_bf16(ah[m], bh[n], acc[m][n], 0, 0, 0);
                acc[m][n] = __builtin_amdgcn_mfma_f32_16x16x32_bf16(ah[m], bl[n], acc[m][n], 0, 0, 0);
                acc[m][n] = __builtin_amdgcn_mfma_f32_16x16x32_bf16(al[m], bh[n], acc[m][n], 0, 0, 0);
            }
        __syncthreads();
    }

    const int lcol = l & 15, lrow = (l >> 4) * 4;
#pragma unroll
    for (int n = 0; n < 4; n++) {
        const int colg = col0 + wc * 64 + n * 16 + lcol;
#pragma unroll
        for (int m = 0; m < 4; m++) {
            const int rowg = row0 + wr * 64 + m * 16 + lrow;
#pragma unroll
            for (int v = 0; v < 4; v++)
                C[(size_t)(rowg + v) * HDIM + colg] = acc[m][n][v];
        }
    }
}

// ---------------------------------------------------------------------------
// MFMA band kernel (verified round 8): block = 16 q-rows, 4 waves split K.
// ---------------------------------------------------------------------------
__global__ __launch_bounds__(256) void band_mfma(const float* __restrict__ q,
                                                 const float* __restrict__ t,
                                                 const float* __restrict__ beta,
                                                 float* __restrict__ band) {
    __shared__ float lds_c[4][16][33];
    const int tid = threadIdx.x;
    const int w = tid >> 6, l = tid & 63;
    const int r0 = blockIdx.x * 16;
    const int b = r0 >> 11;
    const int i0 = r0 & (LSEQ - 1);
    const int fr = l & 15;
    const int kb = (l >> 4) * 8;

    const float* qrow = q + (size_t)(r0 + fr) * HDIM;
    const float* tbase = t + (size_t)b * LSEQ * HDIM;

    const int j0 = i0 - 4 + fr;
    const int j1 = i0 + 12 + fr;
    const int j0c = min(max(j0, 0), LSEQ - 1);
    const int j1c = min(max(j1, 0), LSEQ - 1);
    const bool v0 = (j0 >= 0) && (j0 < LSEQ);
    const bool v1 = (j1 >= 0) && (j1 < LSEQ);
    const bool interior = (i0 >= 4) && (i0 + 19 < LSEQ);
    const float4 fz = {0.f, 0.f, 0.f, 0.f};

    f32x4 c0 = {0.f, 0.f, 0.f, 0.f};
    f32x4 c1 = {0.f, 0.f, 0.f, 0.f};

#pragma unroll 2
    for (int ks = 0; ks < 8; ks++) {
        const int k0 = w * 256 + ks * 32 + kb;
        float4 qa = *reinterpret_cast<const float4*>(qrow + k0);
        float4 qb = *reinterpret_cast<const float4*>(qrow + k0 + 4);
        float4 t0a = *reinterpret_cast<const float4*>(tbase + (size_t)j0c * HDIM + k0);
        float4 t0b = *reinterpret_cast<const float4*>(tbase + (size_t)j0c * HDIM + k0 + 4);
        float4 t1a = *reinterpret_cast<const float4*>(tbase + (size_t)j1c * HDIM + k0);
        float4 t1b = *reinterpret_cast<const float4*>(tbase + (size_t)j1c * HDIM + k0 + 4);
        if (!interior) {
            if (!v0) { t0a = fz; t0b = fz; }
            if (!v1) { t1a = fz; t1b = fz; }
        }
        bf16x8 ah, al, b0h, b0l, b1h, b1l;
        split8(qa, qb, ah, al);
        split8(t0a, t0b, b0h, b0l);
        split8(t1a, t1b, b1h, b1l);
        c0 = __builtin_amdgcn_mfma_f32_16x16x32_bf16(ah, b0h, c0, 0, 0, 0);
        c0 = __builtin_amdgcn_mfma_f32_16x16x32_bf16(ah, b0l, c0, 0, 0, 0);
        c0 = __builtin_amdgcn_mfma_f32_16x16x32_bf16(al, b0h, c0, 0, 0, 0);
        c1 = __builtin_amdgcn_mfma_f32_16x16x32_bf16(ah, b1h, c1, 0, 0, 0);
        c1 = __builtin_amdgcn_mfma_f32_16x16x32_bf16(ah, b1l, c1, 0, 0, 0);
        c1 = __builtin_amdgcn_mfma_f32_16x16x32_bf16(al, b1h, c1, 0, 0, 0);
    }

#pragma unroll
    for (int v = 0; v < 4; v++) {
        lds_c[w][(l >> 4) * 4 + v][fr] = c0[v];
        lds_c[w][(l >> 4) * 4 + v][16 + fr] = c1[v];
    }
    __syncthreads();

#pragma unroll
    for (int e = tid; e < 512; e += 256) {
        const int rr = e >> 5, cc = e & 31;
        lds_c[0][rr][cc] = lds_c[0][rr][cc] + lds_c[1][rr][cc] +
                           lds_c[2][rr][cc] + lds_c[3][rr][cc];
    }
    __syncthreads();

    if (tid < 16) {
        const int il = i0 + tid;
        const int ig = r0 + tid;
        float lg[NBAND];
#pragma unroll
        for (int d = 0; d < NBAND; d++) {
            const int j = il + d - 4;
            lg[d] = (j >= 0 && j < LSEQ)
                    ? lds_c[0][tid][tid + d] + beta[(size_t)b * LSEQ + j]
                    : -1e30f;
        }
        float m = -1e30f;
#pragma unroll
        for (int d = 0; d < NBAND; d++) m = fmaxf(m, lg[d]);
        float p[NBAND], s = 0.f;
#pragma unroll
        for (int d = 0; d < NBAND; d++) { p[d] = expf(lg[d] - m); s += p[d]; }
        const float inv = 1.f / s;
#pragma unroll
        for (int d = 0; d < NBAND; d++) band[(size_t)ig * NBAND + d] = p[d] * inv;
    }
}

// ---------------------------------------------------------------------------
// Expand band probs into dense [B, L, L] output.
// ---------------------------------------------------------------------------
__global__ __launch_bounds__(256) void expand_band(const float* __restrict__ band,
                                                   float* __restrict__ out) {
    const size_t idx4 = (size_t)blockIdx.x * 256 + threadIdx.x;
    const size_t flat = idx4 * 4;
    const int j0 = (int)(flat & (LSEQ - 1));
    const size_t row = flat >> 11;
    const int i = (int)(row & (LSEQ - 1));
    float v[4];
#pragma unroll
    for (int s = 0; s < 4; s++) {
        const int dj = (j0 + s) - i + 4;
        v[s] = (dj >= 0 && dj < NBAND) ? band[row * NBAND + dj] : 0.f;
    }
    float4 o = {v[0], v[1], v[2], v[3]};
    *reinterpret_cast<float4*>(&out[flat]) = o;
}

// ---------------------------------------------------------------------------
// Fallback fp32 path (ws too small).
// ---------------------------------------------------------------------------
__global__ __launch_bounds__(256) void gemm_nt_bias(const float* __restrict__ A,
                                                    const float* __restrict__ B,
                                                    const float* __restrict__ bias,
                                                    float* __restrict__ C) {
    __shared__ float As[8][132];
    __shared__ float Bs[8][132];
    const int tid = threadIdx.x;
    const int row0 = blockIdx.x * 128, col0 = blockIdx.y * 128;
    const int lr = tid >> 1, lc = (tid & 1) * 4;
    const int tx = tid & 15, ty = tid >> 4;
    float acc[2][2][4][4];
#pragma unroll
    for (int a = 0; a < 2; a++)
#pragma unroll
        for (int b = 0; b < 2; b++)
#pragma unroll
            for (int c = 0; c < 4; c++)
#pragma unroll
                for (int d = 0; d < 4; d++) acc[a][b][c][d] = 0.f;
    for (int k0 = 0; k0 < HDIM; k0 += 8) {
        float4 av = *reinterpret_cast<const float4*>(&A[(size_t)(row0 + lr) * HDIM + k0 + lc]);
        float4 bv = *reinterpret_cast<const float4*>(&B[(size_t)(col0 + lr) * HDIM + k0 + lc]);
        __syncthreads();
        As[lc + 0][lr] = av.x; As[lc + 1][lr] = av.y; As[lc + 2][lr] = av.z; As[lc + 3][lr] = av.w;
        Bs[lc + 0][lr] = bv.x; Bs[lc + 1][lr] = bv.y; Bs[lc + 2][lr] = bv.z; Bs[lc + 3][lr] = bv.w;
        __syncthreads();
#pragma unroll
        for (int kk = 0; kk < 8; kk++) {
            float4 a0 = *reinterpret_cast<const float4*>(&As[kk][ty * 4]);
            float4 a1 = *reinterpret_cast<const float4*>(&As[kk][64 + ty * 4]);
            float4 b0 = *reinterpret_cast<const float4*>(&Bs[kk][tx * 4]);
            float4 b1 = *reinterpret_cast<const float4*>(&Bs[kk][64 + tx * 4]);
            float am[2][4] = {{a0.x, a0.y, a0.z, a0.w}, {a1.x, a1.y, a1.z, a1.w}};
            float bw[2][4] = {{b0.x, b0.y, b0.z, b0.w}, {b1.x, b1.y, b1.z, b1.w}};
#pragma unroll
            for (int mi = 0; mi < 2; mi++)
#pragma unroll
                for (int ni = 0; ni < 2; ni++)
#pragma unroll
                    for (int mm = 0; mm < 4; mm++)
#pragma unroll
                        for (int nn = 0; nn < 4; nn++)
                            acc[mi][ni][mm][nn] += am[mi][mm] * bw[ni][nn];
        }
    }
#pragma unroll
    for (int mi = 0; mi < 2; mi++)
#pragma unroll
        for (int mm = 0; mm < 4; mm++) {
            const int r = row0 + mi * 64 + ty * 4 + mm;
#pragma unroll
            for (int ni = 0; ni < 2; ni++) {
                const int c = col0 + ni * 64 + tx * 4;
                float4 o;
                o.x = acc[mi][ni][mm][0] + bias[c + 0];
                o.y = acc[mi][ni][mm][1] + bias[c + 1];
                o.z = acc[mi][ni][mm][2] + bias[c + 2];
                o.w = acc[mi][ni][mm][3] + bias[c + 3];
                *reinterpret_cast<float4*>(&C[(size_t)r * HDIM + c]) = o;
            }
        }
}

__global__ __launch_bounds__(256) void band_softmax(const float* __restrict__ qs,
                                                    const float* __restrict__ ks,
                                                    float* __restrict__ band) {
    const int wave = threadIdx.x >> 6;
    const int lane = threadIdx.x & 63;
    const int r = blockIdx.x * 4 + wave;
    const int b = r >> 11;
    const int i = r & (LSEQ - 1);
    const float* qrow = qs + (size_t)r * HDIM;
    const float* kbase = ks + (size_t)b * LSEQ * HDIM;
    float acc[NBAND];
#pragma unroll
    for (int d = 0; d < NBAND; d++) acc[d] = 0.f;
    for (int h = lane; h < HDIM; h += 64) {
        const float qv = qrow[h];
#pragma unroll
        for (int d = 0; d < NBAND; d++) {
            const int j = i + d - 4;
            if (j >= 0 && j < LSEQ)
                acc[d] += qv * kbase[(size_t)j * HDIM + h];
        }
    }
#pragma unroll
    for (int d = 0; d < NBAND; d++) {
        float v = acc[d];
#pragma unroll
        for (int off = 32; off > 0; off >>= 1) v += __shfl_xor(v, off, 64);
        acc[d] = v;
    }
    if (lane == 0) {
        float m = -1e30f;
#pragma unroll
        for (int d = 0; d < NBAND; d++) {
            const int j = i + d - 4;
            if (j >= 0 && j < LSEQ) m = fmaxf(m, acc[d]);
        }
        float p[NBAND];
        float s = 0.f;
#pragma unroll
        for (int d = 0; d < NBAND; d++) {
            const int j = i + d - 4;
            p[d] = (j >= 0 && j < LSEQ) ? expf(acc[d] - m) : 0.f;
            s += p[d];
        }
        const float inv = 1.f / s;
#pragma unroll
        for (int d = 0; d < NBAND; d++) band[(size_t)r * NBAND + d] = p[d] * inv;
    }
}

extern "C" void kernel_launch(void* const* d_in, const int* in_sizes, int n_in,
                              void* d_out, int out_size, void* d_ws, size_t ws_size,
                              hipStream_t stream) {
    const float* q  = (const float*)d_in[0];
    const float* k  = (const float*)d_in[1];
    const float* Wq = (const float*)d_in[2];
    const float* bq = (const float*)d_in[3];
    const float* Wk = (const float*)d_in[4];
    const float* bk = (const float*)d_in[5];
    float* out = (float*)d_out;

    // ---- workspace layout (~36.6 MB, proven available) ----
    const size_t bandB = (size_t)ROWS * NBAND * sizeof(float);
    char* p = (char*)d_ws;
    float* band = (float*)p;                 p += bandB;
    unsigned short* Xhi = (unsigned short*)p; p += (size_t)ROWS * HDIM * 2;   // 16 MB
    unsigned short* Xlo = (unsigned short*)p; p += (size_t)ROWS * HDIM * 2;   // 16 MB
    unsigned short* Mhi = (unsigned short*)p; p += (size_t)HDIM * HDIM * 2;   // 2 MB
    unsigned short* Mlo = (unsigned short*)p; p += (size_t)HDIM * HDIM * 2;   // 2 MB
    float* w        = (float*)p;             p += HDIM * sizeof(float);
    float* wpart    = (float*)p;             p += 64 * HDIM * sizeof(float);
    float* beta     = (float*)p;             p += ROWS * sizeof(float);
    const size_t need = (size_t)(p - (char*)d_ws);

    // WqT/WkT bf16 splits live in the (not-yet-written) Xhi region
    unsigned short* WqTh = Xhi;
    unsigned short* WqTl = Xhi + (size_t)HDIM * HDIM;
    unsigned short* WkTh = Xhi + 2 * (size_t)HDIM * HDIM;
    unsigned short* WkTl = Xhi + 3 * (size_t)HDIM * HDIM;

    // d_out scratch: t at [0, 8.4M floats); Mparts at [8.4M, 16.8M)
    float* t = out;
    float* Mparts = out + (size_t)ROWS * HDIM;

    if (ws_size >= need) {
        wpart_kernel<<<64, 256, 0, stream>>>(Wk, bq, wpart);
        wreduce<<<4, 256, 0, stream>>>(wpart, w);
        dim3 tg(16, 16, 2);
        transpose_convert<<<tg, 256, 0, stream>>>(Wq, Wk, WqTh, WqTl, WkTh, WkTl);
        dim3 mg(8, 8, 8);
        gemm_part<<<mg, 256, 0, stream>>>(WqTh, WqTl, WkTh, WkTl, Mparts);
        reduceM_convert<<<HDIM * HDIM / 4 / 256, 256, 0, stream>>>(Mparts, Mhi, Mlo);
        convert_k_beta<<<ROWS, 256, 0, stream>>>(k, w, Xhi, Xlo, beta);
        dim3 gg(ROWS / 256, HDIM / 128);
        gemm_t2<<<gg, 512, 0, stream>>>(Xhi, Xlo, Mhi, Mlo, t);
        band_mfma<<<ROWS / 16, 256, 0, stream>>>(q, t, beta, band);
        expand_band<<<(size_t)ROWS * LSEQ / 4 / 256, 256, 0, stream>>>(band, out);
    } else {
        float* qs = out;
        float* ks = out + (size_t)ROWS * HDIM;
        dim3 gg(ROWS / 128, HDIM / 128);
        gemm_nt_bias<<<gg, 256, 0, stream>>>(q, Wq, bq, qs);
        gemm_nt_bias<<<gg, 256, 0, stream>>>(k, Wk, bk, ks);
        band_softmax<<<ROWS / 4, 256, 0, stream>>>(qs, ks, band);
        expand_band<<<(size_t)ROWS * LSEQ / 4 / 256, 256, 0, stream>>>(band, out);
    }
}

// Round 10
// 143.599 us; speedup vs baseline: 1.0645x; 1.0645x over previous
//
#include <hip/hip_runtime.h>
#include <math.h>

#define LSEQ 2048
#define HDIM 1024
#define BATCH 4
#define ROWS (BATCH * LSEQ)   // 8192
#define NBAND 9               // |i-j| <= 4

typedef __attribute__((ext_vector_type(8))) short bf16x8;
typedef __attribute__((ext_vector_type(4))) float f32x4;
typedef __attribute__((ext_vector_type(8))) unsigned short u16x8;

#define AS3 __attribute__((address_space(3)))
#define AS1 __attribute__((address_space(1)))

__device__ __forceinline__ void gload16(const void* gp, void* lp) {
    __builtin_amdgcn_global_load_lds((AS1 const unsigned*)gp, (AS3 unsigned*)lp, 16, 0, 0);
}

__device__ __forceinline__ unsigned short f2bf(float x) {
    unsigned u = __float_as_uint(x);
    u += 0x7FFFu + ((u >> 16) & 1u);
    return (unsigned short)(u >> 16);
}
__device__ __forceinline__ float bf2f(unsigned short h) {
    return __uint_as_float(((unsigned)h) << 16);
}

// split 8 fp32 (two float4) into bf16 hi/lo fragments
__device__ __forceinline__ void split8(float4 a, float4 b, bf16x8& hi, bf16x8& lo) {
    float v[8] = {a.x, a.y, a.z, a.w, b.x, b.y, b.z, b.w};
#pragma unroll
    for (int j = 0; j < 8; j++) {
        unsigned short h = f2bf(v[j]);
        hi[j] = (short)h;
        lo[j] = (short)f2bf(v[j] - bf2f(h));
    }
}

// ---------------------------------------------------------------------------
// w partial: wpart[blk][c] = sum_{h in blk range} Wk[h,c] * bq[h] (64 blocks)
// ---------------------------------------------------------------------------
__global__ __launch_bounds__(256) void wpart_kernel(const float* __restrict__ Wk,
                                                    const float* __restrict__ bq,
                                                    float* __restrict__ wpart) {
    const int b = blockIdx.x;
    const int c0 = threadIdx.x * 4;
    float4 acc = {0.f, 0.f, 0.f, 0.f};
#pragma unroll
    for (int hh = 0; hh < 16; hh++) {
        const int h = b * 16 + hh;
        const float s = bq[h];
        float4 v = *reinterpret_cast<const float4*>(&Wk[(size_t)h * HDIM + c0]);
        acc.x += v.x * s; acc.y += v.y * s; acc.z += v.z * s; acc.w += v.w * s;
    }
    *reinterpret_cast<float4*>(&wpart[(size_t)b * HDIM + c0]) = acc;
}

__global__ __launch_bounds__(256) void wreduce(const float* __restrict__ wpart,
                                               float* __restrict__ w) {
    const int c = blockIdx.x * 256 + threadIdx.x;
    float s = 0.f;
#pragma unroll
    for (int b = 0; b < 64; b++) s += wpart[(size_t)b * HDIM + c];
    w[c] = s;
}

// ---------------------------------------------------------------------------
// Transposed split-convert: dst[n,h] = split(src[h,n]); z=0 -> Wq, z=1 -> Wk
// ---------------------------------------------------------------------------
__global__ __launch_bounds__(256) void transpose_convert(const float* __restrict__ Wq,
                                                         const float* __restrict__ Wk,
                                                         unsigned short* __restrict__ qhi,
                                                         unsigned short* __restrict__ qlo,
                                                         unsigned short* __restrict__ khi,
                                                         unsigned short* __restrict__ klo) {
    __shared__ float tile[64][65];
    const int z = blockIdx.z;
    const float* src = z ? Wk : Wq;
    unsigned short* dh = z ? khi : qhi;
    unsigned short* dl = z ? klo : qlo;
    const int n0 = blockIdx.x * 64;
    const int h0 = blockIdx.y * 64;
    const int tid = threadIdx.x;

#pragma unroll
    for (int p = 0; p < 4; p++) {
        const int h = p * 16 + (tid >> 4);
        const int n = (tid & 15) * 4;
        float4 v = *reinterpret_cast<const float4*>(&src[(size_t)(h0 + h) * HDIM + n0 + n]);
        tile[h][n + 0] = v.x; tile[h][n + 1] = v.y; tile[h][n + 2] = v.z; tile[h][n + 3] = v.w;
    }
    __syncthreads();
#pragma unroll
    for (int p = 0; p < 2; p++) {
        const int n = p * 32 + (tid >> 3);
        const int h = (tid & 7) * 8;
        u16x8 hv, lv;
#pragma unroll
        for (int j = 0; j < 8; j++) {
            float x = tile[h + j][n];
            unsigned short hb = f2bf(x);
            hv[j] = hb;
            lv[j] = f2bf(x - bf2f(hb));
        }
        *reinterpret_cast<u16x8*>(&dh[(size_t)(n0 + n) * HDIM + h0 + h]) = hv;
        *reinterpret_cast<u16x8*>(&dl[(size_t)(n0 + n) * HDIM + h0 + h]) = lv;
    }
}

// ---------------------------------------------------------------------------
// Fused: split-convert k rows to bf16 hi/lo AND beta[r] = k_r . w
// ---------------------------------------------------------------------------
__global__ __launch_bounds__(256) void convert_k_beta(const float* __restrict__ k,
                                                      const float* __restrict__ w,
                                                      unsigned short* __restrict__ Xhi,
                                                      unsigned short* __restrict__ Xlo,
                                                      float* __restrict__ beta) {
    __shared__ float red[4];
    const int r = blockIdx.x;
    const int t = threadIdx.x;
    float4 v = *reinterpret_cast<const float4*>(&k[(size_t)r * HDIM + t * 4]);
    float4 wv = *reinterpret_cast<const float4*>(&w[t * 4]);
    ushort4 h, l;
    h.x = f2bf(v.x); l.x = f2bf(v.x - bf2f(h.x));
    h.y = f2bf(v.y); l.y = f2bf(v.y - bf2f(h.y));
    h.z = f2bf(v.z); l.z = f2bf(v.z - bf2f(h.z));
    h.w = f2bf(v.w); l.w = f2bf(v.w - bf2f(h.w));
    reinterpret_cast<ushort4*>(Xhi)[(size_t)r * 256 + t] = h;
    reinterpret_cast<ushort4*>(Xlo)[(size_t)r * 256 + t] = l;
    float d = v.x * wv.x + v.y * wv.y + v.z * wv.z + v.w * wv.w;
#pragma unroll
    for (int off = 32; off > 0; off >>= 1) d += __shfl_xor(d, off, 64);
    if ((t & 63) == 0) red[t >> 6] = d;
    __syncthreads();
    if (t == 0) beta[r] = red[0] + red[1] + red[2] + red[3];
}

// ---------------------------------------------------------------------------
// Split-K GEMM for M = WqT @ WkT^T: grid (8,8,4), K-slice 256 each.
// ---------------------------------------------------------------------------
__global__ __launch_bounds__(256, 2) void gemm_part(
        const unsigned short* __restrict__ Ahi, const unsigned short* __restrict__ Alo,
        const unsigned short* __restrict__ Bhi, const unsigned short* __restrict__ Blo,
        float* __restrict__ Cparts) {
    __shared__ unsigned short sh[4 * 4096];
    const int AHI = 0, ALO = 4096, BHI = 8192, BLO = 12288;
    const int tid = threadIdx.x;
    const int w = tid >> 6, l = tid & 63;
    const int wr = w >> 1, wc = w & 1;
    const int row0 = blockIdx.x * 128, col0 = blockIdx.y * 128;
    const int kbeg = blockIdx.z * 256;
    float* C = Cparts + (size_t)blockIdx.z * HDIM * HDIM;
    const int srow0 = (l >> 2), scbp = l & 3;

    f32x4 acc[4][4];
#pragma unroll
    for (int m = 0; m < 4; m++)
#pragma unroll
        for (int n = 0; n < 4; n++) acc[m][n] = (f32x4){0.f, 0.f, 0.f, 0.f};

    const int fr_a[4] = {wr * 64 + (l & 15), wr * 64 + 16 + (l & 15),
                         wr * 64 + 32 + (l & 15), wr * 64 + 48 + (l & 15)};
    const int fr_b[4] = {wc * 64 + (l & 15), wc * 64 + 16 + (l & 15),
                         wc * 64 + 32 + (l & 15), wc * 64 + 48 + (l & 15)};
    const int cb = l >> 4;

    for (int k0 = kbeg; k0 < kbeg + 256; k0 += 32) {
#pragma unroll
        for (int i = 0; i < 2; i++) {
            const int seg = i * 4 + w;
            const int row = seg * 16 + srow0;
            const int cbs = scbp ^ ((row >> 1) & 3);
            gload16(Ahi + (size_t)(row0 + row) * HDIM + k0 + cbs * 8, &sh[AHI + seg * 512]);
            gload16(Alo + (size_t)(row0 + row) * HDIM + k0 + cbs * 8, &sh[ALO + seg * 512]);
            gload16(Bhi + (size_t)(col0 + row) * HDIM + k0 + cbs * 8, &sh[BHI + seg * 512]);
            gload16(Blo + (size_t)(col0 + row) * HDIM + k0 + cbs * 8, &sh[BLO + seg * 512]);
        }
        __syncthreads();

        bf16x8 ah[4], al[4], bh[4], bl[4];
#pragma unroll
        for (int m = 0; m < 4; m++) {
            const int r = fr_a[m];
            const int cbs = cb ^ ((r >> 1) & 3);
            ah[m] = *reinterpret_cast<const bf16x8*>(&sh[AHI + r * 32 + cbs * 8]);
            al[m] = *reinterpret_cast<const bf16x8*>(&sh[ALO + r * 32 + cbs * 8]);
        }
#pragma unroll
        for (int n = 0; n < 4; n++) {
            const int r = fr_b[n];
            const int cbs = cb ^ ((r >> 1) & 3);
            bh[n] = *reinterpret_cast<const bf16x8*>(&sh[BHI + r * 32 + cbs * 8]);
            bl[n] = *reinterpret_cast<const bf16x8*>(&sh[BLO + r * 32 + cbs * 8]);
        }
#pragma unroll
        for (int m = 0; m < 4; m++)
#pragma unroll
            for (int n = 0; n < 4; n++) {
                acc[m][n] = __builtin_amdgcn_mfma_f32_16x16x32_bf16(ah[m], bh[n], acc[m][n], 0, 0, 0);
                acc[m][n] = __builtin_amdgcn_mfma_f32_16x16x32_bf16(ah[m], bl[n], acc[m][n], 0, 0, 0);
                acc[m][n] = __builtin_amdgcn_mfma_f32_16x16x32_bf16(al[m], bh[n], acc[m][n], 0, 0, 0);
            }
        __syncthreads();
    }

    const int lcol = l & 15, lrow = (l >> 4) * 4;
#pragma unroll
    for (int n = 0; n < 4; n++) {
        const int colg = col0 + wc * 64 + n * 16 + lcol;
#pragma unroll
        for (int m = 0; m < 4; m++) {
            const int rowg = row0 + wr * 64 + m * 16 + lrow;
#pragma unroll
            for (int v = 0; v < 4; v++)
                C[(size_t)(rowg + v) * HDIM + colg] = acc[m][n][v];
        }
    }
}

// ---------------------------------------------------------------------------
// Reduce 4 M-parts and split-convert to bf16 hi/lo.
// ---------------------------------------------------------------------------
__global__ __launch_bounds__(256) void reduceM_convert(const float* __restrict__ Mparts,
                                                       unsigned short* __restrict__ Mhi,
                                                       unsigned short* __restrict__ Mlo) {
    const int idx4 = blockIdx.x * 256 + threadIdx.x;
    float4 s = {0.f, 0.f, 0.f, 0.f};
#pragma unroll
    for (int z = 0; z < 4; z++) {
        float4 v = reinterpret_cast<const float4*>(Mparts + (size_t)z * HDIM * HDIM)[idx4];
        s.x += v.x; s.y += v.y; s.z += v.z; s.w += v.w;
    }
    ushort4 h, l;
    h.x = f2bf(s.x); l.x = f2bf(s.x - bf2f(h.x));
    h.y = f2bf(s.y); l.y = f2bf(s.y - bf2f(h.y));
    h.z = f2bf(s.z); l.z = f2bf(s.z - bf2f(h.z));
    h.w = f2bf(s.w); l.w = f2bf(s.w - bf2f(h.w));
    reinterpret_cast<ushort4*>(Mhi)[idx4] = h;
    reinterpret_cast<ushort4*>(Mlo)[idx4] = l;
}

// ---------------------------------------------------------------------------
// Big GEMM (t = K @ M^T), 128x128 tile, BK=32, 4 waves (verified round 3-8)
// + XCD-aware bijective blockIdx swizzle (512 blocks % 8 == 0): each XCD
// gets one contiguous column-stripe so its 0.5 MB B-panel stays L2-resident.
// ---------------------------------------------------------------------------
__global__ __launch_bounds__(256, 2) void gemm_t(
        const unsigned short* __restrict__ Ahi, const unsigned short* __restrict__ Alo,
        const unsigned short* __restrict__ Bhi, const unsigned short* __restrict__ Blo,
        float* __restrict__ C) {
    __shared__ unsigned short sh[4 * 4096];
    const int AHI = 0, ALO = 4096, BHI = 8192, BLO = 12288;
    const int tid = threadIdx.x;
    const int w = tid >> 6, l = tid & 63;
    const int wr = w >> 1, wc = w & 1;

    // XCD swizzle: bid -> (xcd = bid&7) owns tiles [xcd*64, xcd*64+64)
    const int bid = blockIdx.y * gridDim.x + blockIdx.x;   // 0..511
    const int swz = (bid & 7) * 64 + (bid >> 3);
    const int row0 = (swz & 63) * 128;                     // 64 row tiles
    const int col0 = (swz >> 6) * 128;                     // 8 col tiles
    const int srow0 = (l >> 2), scbp = l & 3;

    f32x4 acc[4][4];
#pragma unroll
    for (int m = 0; m < 4; m++)
#pragma unroll
        for (int n = 0; n < 4; n++) acc[m][n] = (f32x4){0.f, 0.f, 0.f, 0.f};

    const int fr_a[4] = {wr * 64 + (l & 15), wr * 64 + 16 + (l & 15),
                         wr * 64 + 32 + (l & 15), wr * 64 + 48 + (l & 15)};
    const int fr_b[4] = {wc * 64 + (l & 15), wc * 64 + 16 + (l & 15),
                         wc * 64 + 32 + (l & 15), wc * 64 + 48 + (l & 15)};
    const int cb = l >> 4;

    for (int k0 = 0; k0 < HDIM; k0 += 32) {
#pragma unroll
        for (int i = 0; i < 2; i++) {
            const int seg = i * 4 + w;
            const int row = seg * 16 + srow0;
            const int cbs = scbp ^ ((row >> 1) & 3);
            gload16(Ahi + (size_t)(row0 + row) * HDIM + k0 + cbs * 8, &sh[AHI + seg * 512]);
            gload16(Alo + (size_t)(row0 + row) * HDIM + k0 + cbs * 8, &sh[ALO + seg * 512]);
            gload16(Bhi + (size_t)(col0 + row) * HDIM + k0 + cbs * 8, &sh[BHI + seg * 512]);
            gload16(Blo + (size_t)(col0 + row) * HDIM + k0 + cbs * 8, &sh[BLO + seg * 512]);
        }
        __syncthreads();

        bf16x8 ah[4], al[4], bh[4], bl[4];
#pragma unroll
        for (int m = 0; m < 4; m++) {
            const int r = fr_a[m];
            const int cbs = cb ^ ((r >> 1) & 3);
            ah[m] = *reinterpret_cast<const bf16x8*>(&sh[AHI + r * 32 + cbs * 8]);
            al[m] = *reinterpret_cast<const bf16x8*>(&sh[ALO + r * 32 + cbs * 8]);
        }
#pragma unroll
        for (int n = 0; n < 4; n++) {
            const int r = fr_b[n];
            const int cbs = cb ^ ((r >> 1) & 3);
            bh[n] = *reinterpret_cast<const bf16x8*>(&sh[BHI + r * 32 + cbs * 8]);
            bl[n] = *reinterpret_cast<const bf16x8*>(&sh[BLO + r * 32 + cbs * 8]);
        }
#pragma unroll
        for (int m = 0; m < 4; m++)
#pragma unroll
            for (int n = 0; n < 4; n++) {
                acc[m][n] = __builtin_amdgcn_mfma_f32_16x16x32_bf16(ah[m], bh[n], acc[m][n], 0, 0, 0);
                acc[m][n] = __builtin_amdgcn_mfma_f32_16x16x32_bf16(ah[m], bl[n], acc[m][n], 0, 0, 0);
                acc[m][n] = __builtin_amdgcn_mfma_f32_16x16x32_bf16(al[m], bh[n], acc[m][n], 0, 0, 0);
            }
        __syncthreads();
    }

    const int lcol = l & 15, lrow = (l >> 4) * 4;
#pragma unroll
    for (int n = 0; n < 4; n++) {
        const int colg = col0 + wc * 64 + n * 16 + lcol;
#pragma unroll
        for (int m = 0; m < 4; m++) {
            const int rowg = row0 + wr * 64 + m * 16 + lrow;
#pragma unroll
            for (int v = 0; v < 4; v++)
                C[(size_t)(rowg + v) * HDIM + colg] = acc[m][n][v];
        }
    }
}

// ---------------------------------------------------------------------------
// MFMA band kernel (verified round 8): block = 16 q-rows, 4 waves split K.
// ---------------------------------------------------------------------------
__global__ __launch_bounds__(256) void band_mfma(const float* __restrict__ q,
                                                 const float* __restrict__ t,
                                                 const float* __restrict__ beta,
                                                 float* __restrict__ band) {
    __shared__ float lds_c[4][16][33];
    const int tid = threadIdx.x;
    const int w = tid >> 6, l = tid & 63;
    const int r0 = blockIdx.x * 16;
    const int b = r0 >> 11;
    const int i0 = r0 & (LSEQ - 1);
    const int fr = l & 15;
    const int kb = (l >> 4) * 8;

    const float* qrow = q + (size_t)(r0 + fr) * HDIM;
    const float* tbase = t + (size_t)b * LSEQ * HDIM;

    const int j0 = i0 - 4 + fr;
    const int j1 = i0 + 12 + fr;
    const int j0c = min(max(j0, 0), LSEQ - 1);
    const int j1c = min(max(j1, 0), LSEQ - 1);
    const bool v0 = (j0 >= 0) && (j0 < LSEQ);
    const bool v1 = (j1 >= 0) && (j1 < LSEQ);
    const bool interior = (i0 >= 4) && (i0 + 19 < LSEQ);
    const float4 fz = {0.f, 0.f, 0.f, 0.f};

    f32x4 c0 = {0.f, 0.f, 0.f, 0.f};
    f32x4 c1 = {0.f, 0.f, 0.f, 0.f};

#pragma unroll 2
    for (int ks = 0; ks < 8; ks++) {
        const int k0 = w * 256 + ks * 32 + kb;
        float4 qa = *reinterpret_cast<const float4*>(qrow + k0);
        float4 qb = *reinterpret_cast<const float4*>(qrow + k0 + 4);
        float4 t0a = *reinterpret_cast<const float4*>(tbase + (size_t)j0c * HDIM + k0);
        float4 t0b = *reinterpret_cast<const float4*>(tbase + (size_t)j0c * HDIM + k0 + 4);
        float4 t1a = *reinterpret_cast<const float4*>(tbase + (size_t)j1c * HDIM + k0);
        float4 t1b = *reinterpret_cast<const float4*>(tbase + (size_t)j1c * HDIM + k0 + 4);
        if (!interior) {
            if (!v0) { t0a = fz; t0b = fz; }
            if (!v1) { t1a = fz; t1b = fz; }
        }
        bf16x8 ah, al, b0h, b0l, b1h, b1l;
        split8(qa, qb, ah, al);
        split8(t0a, t0b, b0h, b0l);
        split8(t1a, t1b, b1h, b1l);
        c0 = __builtin_amdgcn_mfma_f32_16x16x32_bf16(ah, b0h, c0, 0, 0, 0);
        c0 = __builtin_amdgcn_mfma_f32_16x16x32_bf16(ah, b0l, c0, 0, 0, 0);
        c0 = __builtin_amdgcn_mfma_f32_16x16x32_bf16(al, b0h, c0, 0, 0, 0);
        c1 = __builtin_amdgcn_mfma_f32_16x16x32_bf16(ah, b1h, c1, 0, 0, 0);
        c1 = __builtin_amdgcn_mfma_f32_16x16x32_bf16(ah, b1l, c1, 0, 0, 0);
        c1 = __builtin_amdgcn_mfma_f32_16x16x32_bf16(al, b1h, c1, 0, 0, 0);
    }

#pragma unroll
    for (int v = 0; v < 4; v++) {
        lds_c[w][(l >> 4) * 4 + v][fr] = c0[v];
        lds_c[w][(l >> 4) * 4 + v][16 + fr] = c1[v];
    }
    __syncthreads();

#pragma unroll
    for (int e = tid; e < 512; e += 256) {
        const int rr = e >> 5, cc = e & 31;
        lds_c[0][rr][cc] = lds_c[0][rr][cc] + lds_c[1][rr][cc] +
                           lds_c[2][rr][cc] + lds_c[3][rr][cc];
    }
    __syncthreads();

    if (tid < 16) {
        const int il = i0 + tid;
        const int ig = r0 + tid;
        float lg[NBAND];
#pragma unroll
        for (int d = 0; d < NBAND; d++) {
            const int j = il + d - 4;
            lg[d] = (j >= 0 && j < LSEQ)
                    ? lds_c[0][tid][tid + d] + beta[(size_t)b * LSEQ + j]
                    : -1e30f;
        }
        float m = -1e30f;
#pragma unroll
        for (int d = 0; d < NBAND; d++) m = fmaxf(m, lg[d]);
        float p[NBAND], s = 0.f;
#pragma unroll
        for (int d = 0; d < NBAND; d++) { p[d] = expf(lg[d] - m); s += p[d]; }
        const float inv = 1.f / s;
#pragma unroll
        for (int d = 0; d < NBAND; d++) band[(size_t)ig * NBAND + d] = p[d] * inv;
    }
}

// ---------------------------------------------------------------------------
// Expand band probs into dense [B, L, L] output.
// ---------------------------------------------------------------------------
__global__ __launch_bounds__(256) void expand_band(const float* __restrict__ band,
                                                   float* __restrict__ out) {
    const size_t idx4 = (size_t)blockIdx.x * 256 + threadIdx.x;
    const size_t flat = idx4 * 4;
    const int j0 = (int)(flat & (LSEQ - 1));
    const size_t row = flat >> 11;
    const int i = (int)(row & (LSEQ - 1));
    float v[4];
#pragma unroll
    for (int s = 0; s < 4; s++) {
        const int dj = (j0 + s) - i + 4;
        v[s] = (dj >= 0 && dj < NBAND) ? band[row * NBAND + dj] : 0.f;
    }
    float4 o = {v[0], v[1], v[2], v[3]};
    *reinterpret_cast<float4*>(&out[flat]) = o;
}

// ---------------------------------------------------------------------------
// Fallback fp32 path (ws too small).
// ---------------------------------------------------------------------------
__global__ __launch_bounds__(256) void gemm_nt_bias(const float* __restrict__ A,
                                                    const float* __restrict__ B,
                                                    const float* __restrict__ bias,
                                                    float* __restrict__ C) {
    __shared__ float As[8][132];
    __shared__ float Bs[8][132];
    const int tid = threadIdx.x;
    const int row0 = blockIdx.x * 128, col0 = blockIdx.y * 128;
    const int lr = tid >> 1, lc = (tid & 1) * 4;
    const int tx = tid & 15, ty = tid >> 4;
    float acc[2][2][4][4];
#pragma unroll
    for (int a = 0; a < 2; a++)
#pragma unroll
        for (int b = 0; b < 2; b++)
#pragma unroll
            for (int c = 0; c < 4; c++)
#pragma unroll
                for (int d = 0; d < 4; d++) acc[a][b][c][d] = 0.f;
    for (int k0 = 0; k0 < HDIM; k0 += 8) {
        float4 av = *reinterpret_cast<const float4*>(&A[(size_t)(row0 + lr) * HDIM + k0 + lc]);
        float4 bv = *reinterpret_cast<const float4*>(&B[(size_t)(col0 + lr) * HDIM + k0 + lc]);
        __syncthreads();
        As[lc + 0][lr] = av.x; As[lc + 1][lr] = av.y; As[lc + 2][lr] = av.z; As[lc + 3][lr] = av.w;
        Bs[lc + 0][lr] = bv.x; Bs[lc + 1][lr] = bv.y; Bs[lc + 2][lr] = bv.z; Bs[lc + 3][lr] = bv.w;
        __syncthreads();
#pragma unroll
        for (int kk = 0; kk < 8; kk++) {
            float4 a0 = *reinterpret_cast<const float4*>(&As[kk][ty * 4]);
            float4 a1 = *reinterpret_cast<const float4*>(&As[kk][64 + ty * 4]);
            float4 b0 = *reinterpret_cast<const float4*>(&Bs[kk][tx * 4]);
            float4 b1 = *reinterpret_cast<const float4*>(&Bs[kk][64 + tx * 4]);
            float am[2][4] = {{a0.x, a0.y, a0.z, a0.w}, {a1.x, a1.y, a1.z, a1.w}};
            float bw[2][4] = {{b0.x, b0.y, b0.z, b0.w}, {b1.x, b1.y, b1.z, b1.w}};
#pragma unroll
            for (int mi = 0; mi < 2; mi++)
#pragma unroll
                for (int ni = 0; ni < 2; ni++)
#pragma unroll
                    for (int mm = 0; mm < 4; mm++)
#pragma unroll
                        for (int nn = 0; nn < 4; nn++)
                            acc[mi][ni][mm][nn] += am[mi][mm] * bw[ni][nn];
        }
    }
#pragma unroll
    for (int mi = 0; mi < 2; mi++)
#pragma unroll
        for (int mm = 0; mm < 4; mm++) {
            const int r = row0 + mi * 64 + ty * 4 + mm;
#pragma unroll
            for (int ni = 0; ni < 2; ni++) {
                const int c = col0 + ni * 64 + tx * 4;
                float4 o;
                o.x = acc[mi][ni][mm][0] + bias[c + 0];
                o.y = acc[mi][ni][mm][1] + bias[c + 1];
                o.z = acc[mi][ni][mm][2] + bias[c + 2];
                o.w = acc[mi][ni][mm][3] + bias[c + 3];
                *reinterpret_cast<float4*>(&C[(size_t)r * HDIM + c]) = o;
            }
        }
}

__global__ __launch_bounds__(256) void band_softmax(const float* __restrict__ qs,
                                                    const float* __restrict__ ks,
                                                    float* __restrict__ band) {
    const int wave = threadIdx.x >> 6;
    const int lane = threadIdx.x & 63;
    const int r = blockIdx.x * 4 + wave;
    const int b = r >> 11;
    const int i = r & (LSEQ - 1);
    const float* qrow = qs + (size_t)r * HDIM;
    const float* kbase = ks + (size_t)b * LSEQ * HDIM;
    float acc[NBAND];
#pragma unroll
    for (int d = 0; d < NBAND; d++) acc[d] = 0.f;
    for (int h = lane; h < HDIM; h += 64) {
        const float qv = qrow[h];
#pragma unroll
        for (int d = 0; d < NBAND; d++) {
            const int j = i + d - 4;
            if (j >= 0 && j < LSEQ)
                acc[d] += qv * kbase[(size_t)j * HDIM + h];
        }
    }
#pragma unroll
    for (int d = 0; d < NBAND; d++) {
        float v = acc[d];
#pragma unroll
        for (int off = 32; off > 0; off >>= 1) v += __shfl_xor(v, off, 64);
        acc[d] = v;
    }
    if (lane == 0) {
        float m = -1e30f;
#pragma unroll
        for (int d = 0; d < NBAND; d++) {
            const int j = i + d - 4;
            if (j >= 0 && j < LSEQ) m = fmaxf(m, acc[d]);
        }
        float p[NBAND];
        float s = 0.f;
#pragma unroll
        for (int d = 0; d < NBAND; d++) {
            const int j = i + d - 4;
            p[d] = (j >= 0 && j < LSEQ) ? expf(acc[d] - m) : 0.f;
            s += p[d];
        }
        const float inv = 1.f / s;
#pragma unroll
        for (int d = 0; d < NBAND; d++) band[(size_t)r * NBAND + d] = p[d] * inv;
    }
}

extern "C" void kernel_launch(void* const* d_in, const int* in_sizes, int n_in,
                              void* d_out, int out_size, void* d_ws, size_t ws_size,
                              hipStream_t stream) {
    const float* q  = (const float*)d_in[0];
    const float* k  = (const float*)d_in[1];
    const float* Wq = (const float*)d_in[2];
    const float* bq = (const float*)d_in[3];
    const float* Wk = (const float*)d_in[4];
    const float* bk = (const float*)d_in[5];
    float* out = (float*)d_out;

    // ---- workspace layout (~36.6 MB, proven available) ----
    const size_t bandB = (size_t)ROWS * NBAND * sizeof(float);
    char* p = (char*)d_ws;
    float* band = (float*)p;                 p += bandB;
    unsigned short* Xhi = (unsigned short*)p; p += (size_t)ROWS * HDIM * 2;   // 16 MB
    unsigned short* Xlo = (unsigned short*)p; p += (size_t)ROWS * HDIM * 2;   // 16 MB
    unsigned short* Mhi = (unsigned short*)p; p += (size_t)HDIM * HDIM * 2;   // 2 MB
    unsigned short* Mlo = (unsigned short*)p; p += (size_t)HDIM * HDIM * 2;   // 2 MB
    float* w        = (float*)p;             p += HDIM * sizeof(float);
    float* wpart    = (float*)p;             p += 64 * HDIM * sizeof(float);
    float* beta     = (float*)p;             p += ROWS * sizeof(float);
    const size_t need = (size_t)(p - (char*)d_ws);

    // WqT/WkT bf16 splits live in the (not-yet-written) Xhi region
    unsigned short* WqTh = Xhi;
    unsigned short* WqTl = Xhi + (size_t)HDIM * HDIM;
    unsigned short* WkTh = Xhi + 2 * (size_t)HDIM * HDIM;
    unsigned short* WkTl = Xhi + 3 * (size_t)HDIM * HDIM;

    // d_out scratch: t at [0, 8.4M floats); Mparts at [8.4M, 12.6M) (4 parts)
    float* t = out;
    float* Mparts = out + (size_t)ROWS * HDIM;

    if (ws_size >= need) {
        wpart_kernel<<<64, 256, 0, stream>>>(Wk, bq, wpart);
        wreduce<<<4, 256, 0, stream>>>(wpart, w);
        dim3 tg(16, 16, 2);
        transpose_convert<<<tg, 256, 0, stream>>>(Wq, Wk, WqTh, WqTl, WkTh, WkTl);
        dim3 mg(8, 8, 4);
        gemm_part<<<mg, 256, 0, stream>>>(WqTh, WqTl, WkTh, WkTl, Mparts);
        reduceM_convert<<<HDIM * HDIM / 4 / 256, 256, 0, stream>>>(Mparts, Mhi, Mlo);
        convert_k_beta<<<ROWS, 256, 0, stream>>>(k, w, Xhi, Xlo, beta);
        dim3 gg(ROWS / 128, HDIM / 128);
        gemm_t<<<gg, 256, 0, stream>>>(Xhi, Xlo, Mhi, Mlo, t);
        band_mfma<<<ROWS / 16, 256, 0, stream>>>(q, t, beta, band);
        expand_band<<<(size_t)ROWS * LSEQ / 4 / 256, 256, 0, stream>>>(band, out);
    } else {
        float* qs = out;
        float* ks = out + (size_t)ROWS * HDIM;
        dim3 gg(ROWS / 128, HDIM / 128);
        gemm_nt_bias<<<gg, 256, 0, stream>>>(q, Wq, bq, qs);
        gemm_nt_bias<<<gg, 256, 0, stream>>>(k, Wk, bk, ks);
        band_softmax<<<ROWS / 4, 256, 0, stream>>>(qs, ks, band);
        expand_band<<<(size_t)ROWS * LSEQ / 4 / 256, 256, 0, stream>>>(band, out);
    }
}

// Round 11
// 139.331 us; speedup vs baseline: 1.0971x; 1.0306x over previous
//
#include <hip/hip_runtime.h>
#include <math.h>

#define LSEQ 2048
#define HDIM 1024
#define BATCH 4
#define ROWS (BATCH * LSEQ)   // 8192
#define NBAND 9               // |i-j| <= 4

typedef __attribute__((ext_vector_type(8))) short bf16x8;
typedef __attribute__((ext_vector_type(4))) float f32x4;
typedef __attribute__((ext_vector_type(8))) unsigned short u16x8;

#define AS3 __attribute__((address_space(3)))
#define AS1 __attribute__((address_space(1)))

__device__ __forceinline__ void gload16(const void* gp, void* lp) {
    __builtin_amdgcn_global_load_lds((AS1 const unsigned*)gp, (AS3 unsigned*)lp, 16, 0, 0);
}

__device__ __forceinline__ unsigned short f2bf(float x) {
    unsigned u = __float_as_uint(x);
    u += 0x7FFFu + ((u >> 16) & 1u);
    return (unsigned short)(u >> 16);
}
__device__ __forceinline__ float bf2f(unsigned short h) {
    return __uint_as_float(((unsigned)h) << 16);
}

// split 8 fp32 (two float4) into bf16 hi/lo fragments
__device__ __forceinline__ void split8(float4 a, float4 b, bf16x8& hi, bf16x8& lo) {
    float v[8] = {a.x, a.y, a.z, a.w, b.x, b.y, b.z, b.w};
#pragma unroll
    for (int j = 0; j < 8; j++) {
        unsigned short h = f2bf(v[j]);
        hi[j] = (short)h;
        lo[j] = (short)f2bf(v[j] - bf2f(h));
    }
}

// ---------------------------------------------------------------------------
// w partial: wpart[blk][c] = sum_{h in blk range} Wk[h,c] * bq[h] (64 blocks)
// ---------------------------------------------------------------------------
__global__ __launch_bounds__(256) void wpart_kernel(const float* __restrict__ Wk,
                                                    const float* __restrict__ bq,
                                                    float* __restrict__ wpart) {
    const int b = blockIdx.x;
    const int c0 = threadIdx.x * 4;
    float4 acc = {0.f, 0.f, 0.f, 0.f};
#pragma unroll
    for (int hh = 0; hh < 16; hh++) {
        const int h = b * 16 + hh;
        const float s = bq[h];
        float4 v = *reinterpret_cast<const float4*>(&Wk[(size_t)h * HDIM + c0]);
        acc.x += v.x * s; acc.y += v.y * s; acc.z += v.z * s; acc.w += v.w * s;
    }
    *reinterpret_cast<float4*>(&wpart[(size_t)b * HDIM + c0]) = acc;
}

__global__ __launch_bounds__(256) void wreduce(const float* __restrict__ wpart,
                                               float* __restrict__ w) {
    const int c = blockIdx.x * 256 + threadIdx.x;
    float s = 0.f;
#pragma unroll
    for (int b = 0; b < 64; b++) s += wpart[(size_t)b * HDIM + c];
    w[c] = s;
}

// ---------------------------------------------------------------------------
// Transposed split-convert: dst[n,h] = split(src[h,n]); z=0 -> Wq, z=1 -> Wk
// ---------------------------------------------------------------------------
__global__ __launch_bounds__(256) void transpose_convert(const float* __restrict__ Wq,
                                                         const float* __restrict__ Wk,
                                                         unsigned short* __restrict__ qhi,
                                                         unsigned short* __restrict__ qlo,
                                                         unsigned short* __restrict__ khi,
                                                         unsigned short* __restrict__ klo) {
    __shared__ float tile[64][65];
    const int z = blockIdx.z;
    const float* src = z ? Wk : Wq;
    unsigned short* dh = z ? khi : qhi;
    unsigned short* dl = z ? klo : qlo;
    const int n0 = blockIdx.x * 64;
    const int h0 = blockIdx.y * 64;
    const int tid = threadIdx.x;

#pragma unroll
    for (int p = 0; p < 4; p++) {
        const int h = p * 16 + (tid >> 4);
        const int n = (tid & 15) * 4;
        float4 v = *reinterpret_cast<const float4*>(&src[(size_t)(h0 + h) * HDIM + n0 + n]);
        tile[h][n + 0] = v.x; tile[h][n + 1] = v.y; tile[h][n + 2] = v.z; tile[h][n + 3] = v.w;
    }
    __syncthreads();
#pragma unroll
    for (int p = 0; p < 2; p++) {
        const int n = p * 32 + (tid >> 3);
        const int h = (tid & 7) * 8;
        u16x8 hv, lv;
#pragma unroll
        for (int j = 0; j < 8; j++) {
            float x = tile[h + j][n];
            unsigned short hb = f2bf(x);
            hv[j] = hb;
            lv[j] = f2bf(x - bf2f(hb));
        }
        *reinterpret_cast<u16x8*>(&dh[(size_t)(n0 + n) * HDIM + h0 + h]) = hv;
        *reinterpret_cast<u16x8*>(&dl[(size_t)(n0 + n) * HDIM + h0 + h]) = lv;
    }
}

// ---------------------------------------------------------------------------
// Fused: split-convert k rows to bf16 hi/lo AND beta[r] = k_r . w
// ---------------------------------------------------------------------------
__global__ __launch_bounds__(256) void convert_k_beta(const float* __restrict__ k,
                                                      const float* __restrict__ w,
                                                      unsigned short* __restrict__ Xhi,
                                                      unsigned short* __restrict__ Xlo,
                                                      float* __restrict__ beta) {
    __shared__ float red[4];
    const int r = blockIdx.x;
    const int t = threadIdx.x;
    float4 v = *reinterpret_cast<const float4*>(&k[(size_t)r * HDIM + t * 4]);
    float4 wv = *reinterpret_cast<const float4*>(&w[t * 4]);
    ushort4 h, l;
    h.x = f2bf(v.x); l.x = f2bf(v.x - bf2f(h.x));
    h.y = f2bf(v.y); l.y = f2bf(v.y - bf2f(h.y));
    h.z = f2bf(v.z); l.z = f2bf(v.z - bf2f(h.z));
    h.w = f2bf(v.w); l.w = f2bf(v.w - bf2f(h.w));
    reinterpret_cast<ushort4*>(Xhi)[(size_t)r * 256 + t] = h;
    reinterpret_cast<ushort4*>(Xlo)[(size_t)r * 256 + t] = l;
    float d = v.x * wv.x + v.y * wv.y + v.z * wv.z + v.w * wv.w;
#pragma unroll
    for (int off = 32; off > 0; off >>= 1) d += __shfl_xor(d, off, 64);
    if ((t & 63) == 0) red[t >> 6] = d;
    __syncthreads();
    if (t == 0) beta[r] = red[0] + red[1] + red[2] + red[3];
}

// ---------------------------------------------------------------------------
// Split-K GEMM for M = WqT @ WkT^T: grid (8,8,4), K-slice 256 each.
// ---------------------------------------------------------------------------
__global__ __launch_bounds__(256, 2) void gemm_part(
        const unsigned short* __restrict__ Ahi, const unsigned short* __restrict__ Alo,
        const unsigned short* __restrict__ Bhi, const unsigned short* __restrict__ Blo,
        float* __restrict__ Cparts) {
    __shared__ unsigned short sh[4 * 4096];
    const int AHI = 0, ALO = 4096, BHI = 8192, BLO = 12288;
    const int tid = threadIdx.x;
    const int w = tid >> 6, l = tid & 63;
    const int wr = w >> 1, wc = w & 1;
    const int row0 = blockIdx.x * 128, col0 = blockIdx.y * 128;
    const int kbeg = blockIdx.z * 256;
    float* C = Cparts + (size_t)blockIdx.z * HDIM * HDIM;
    const int srow0 = (l >> 2), scbp = l & 3;

    f32x4 acc[4][4];
#pragma unroll
    for (int m = 0; m < 4; m++)
#pragma unroll
        for (int n = 0; n < 4; n++) acc[m][n] = (f32x4){0.f, 0.f, 0.f, 0.f};

    const int fr_a[4] = {wr * 64 + (l & 15), wr * 64 + 16 + (l & 15),
                         wr * 64 + 32 + (l & 15), wr * 64 + 48 + (l & 15)};
    const int fr_b[4] = {wc * 64 + (l & 15), wc * 64 + 16 + (l & 15),
                         wc * 64 + 32 + (l & 15), wc * 64 + 48 + (l & 15)};
    const int cb = l >> 4;

    for (int k0 = kbeg; k0 < kbeg + 256; k0 += 32) {
#pragma unroll
        for (int i = 0; i < 2; i++) {
            const int seg = i * 4 + w;
            const int row = seg * 16 + srow0;
            const int cbs = scbp ^ ((row >> 1) & 3);
            gload16(Ahi + (size_t)(row0 + row) * HDIM + k0 + cbs * 8, &sh[AHI + seg * 512]);
            gload16(Alo + (size_t)(row0 + row) * HDIM + k0 + cbs * 8, &sh[ALO + seg * 512]);
            gload16(Bhi + (size_t)(col0 + row) * HDIM + k0 + cbs * 8, &sh[BHI + seg * 512]);
            gload16(Blo + (size_t)(col0 + row) * HDIM + k0 + cbs * 8, &sh[BLO + seg * 512]);
        }
        __syncthreads();

        bf16x8 ah[4], al[4], bh[4], bl[4];
#pragma unroll
        for (int m = 0; m < 4; m++) {
            const int r = fr_a[m];
            const int cbs = cb ^ ((r >> 1) & 3);
            ah[m] = *reinterpret_cast<const bf16x8*>(&sh[AHI + r * 32 + cbs * 8]);
            al[m] = *reinterpret_cast<const bf16x8*>(&sh[ALO + r * 32 + cbs * 8]);
        }
#pragma unroll
        for (int n = 0; n < 4; n++) {
            const int r = fr_b[n];
            const int cbs = cb ^ ((r >> 1) & 3);
            bh[n] = *reinterpret_cast<const bf16x8*>(&sh[BHI + r * 32 + cbs * 8]);
            bl[n] = *reinterpret_cast<const bf16x8*>(&sh[BLO + r * 32 + cbs * 8]);
        }
#pragma unroll
        for (int m = 0; m < 4; m++)
#pragma unroll
            for (int n = 0; n < 4; n++) {
                acc[m][n] = __builtin_amdgcn_mfma_f32_16x16x32_bf16(ah[m], bh[n], acc[m][n], 0, 0, 0);
                acc[m][n] = __builtin_amdgcn_mfma_f32_16x16x32_bf16(ah[m], bl[n], acc[m][n], 0, 0, 0);
                acc[m][n] = __builtin_amdgcn_mfma_f32_16x16x32_bf16(al[m], bh[n], acc[m][n], 0, 0, 0);
            }
        __syncthreads();
    }

    const int lcol = l & 15, lrow = (l >> 4) * 4;
#pragma unroll
    for (int n = 0; n < 4; n++) {
        const int colg = col0 + wc * 64 + n * 16 + lcol;
#pragma unroll
        for (int m = 0; m < 4; m++) {
            const int rowg = row0 + wr * 64 + m * 16 + lrow;
#pragma unroll
            for (int v = 0; v < 4; v++)
                C[(size_t)(rowg + v) * HDIM + colg] = acc[m][n][v];
        }
    }
}

// ---------------------------------------------------------------------------
// Reduce 4 M-parts and split-convert to bf16 hi/lo.
// ---------------------------------------------------------------------------
__global__ __launch_bounds__(256) void reduceM_convert(const float* __restrict__ Mparts,
                                                       unsigned short* __restrict__ Mhi,
                                                       unsigned short* __restrict__ Mlo) {
    const int idx4 = blockIdx.x * 256 + threadIdx.x;
    float4 s = {0.f, 0.f, 0.f, 0.f};
#pragma unroll
    for (int z = 0; z < 4; z++) {
        float4 v = reinterpret_cast<const float4*>(Mparts + (size_t)z * HDIM * HDIM)[idx4];
        s.x += v.x; s.y += v.y; s.z += v.z; s.w += v.w;
    }
    ushort4 h, l;
    h.x = f2bf(s.x); l.x = f2bf(s.x - bf2f(h.x));
    h.y = f2bf(s.y); l.y = f2bf(s.y - bf2f(h.y));
    h.z = f2bf(s.z); l.z = f2bf(s.z - bf2f(h.z));
    h.w = f2bf(s.w); l.w = f2bf(s.w - bf2f(h.w));
    reinterpret_cast<ushort4*>(Mhi)[idx4] = h;
    reinterpret_cast<ushort4*>(Mlo)[idx4] = l;
}

// ---------------------------------------------------------------------------
// Big GEMM (t = K @ M^T), 128x128 tile, BK=32, 4 waves. NATURAL block
// mapping (grid (64,8)): gridDim.x=64 pins row-tile r to XCD r%8 for every
// col -> A-panels are per-XCD L2-resident (round-10 lesson: do NOT swizzle).
// NEW: double-buffered LDS, stage(k+1) issued BEFORE compute(k), single
// barrier per iter -> staging L2 latency/BW overlaps the MFMA block.
// ---------------------------------------------------------------------------
__global__ __launch_bounds__(256, 2) void gemm_t(
        const unsigned short* __restrict__ Ahi, const unsigned short* __restrict__ Alo,
        const unsigned short* __restrict__ Bhi, const unsigned short* __restrict__ Blo,
        float* __restrict__ C) {
    __shared__ unsigned short sh[2][16384];   // 2 x 32 KB
    const int AHI = 0, ALO = 4096, BHI = 8192, BLO = 12288;
    const int tid = threadIdx.x;
    const int w = tid >> 6, l = tid & 63;
    const int wr = w >> 1, wc = w & 1;
    const int row0 = blockIdx.x * 128, col0 = blockIdx.y * 128;
    const int srow0 = (l >> 2), scbp = l & 3;

    f32x4 acc[4][4];
#pragma unroll
    for (int m = 0; m < 4; m++)
#pragma unroll
        for (int n = 0; n < 4; n++) acc[m][n] = (f32x4){0.f, 0.f, 0.f, 0.f};

    const int fr_a[4] = {wr * 64 + (l & 15), wr * 64 + 16 + (l & 15),
                         wr * 64 + 32 + (l & 15), wr * 64 + 48 + (l & 15)};
    const int fr_b[4] = {wc * 64 + (l & 15), wc * 64 + 16 + (l & 15),
                         wc * 64 + 32 + (l & 15), wc * 64 + 48 + (l & 15)};
    const int cb = l >> 4;

    // stage K-step k0 into buffer buf (8 gload16 per thread)
    auto stage = [&](int buf, int k0) {
#pragma unroll
        for (int i = 0; i < 2; i++) {
            const int seg = i * 4 + w;
            const int row = seg * 16 + srow0;
            const int cbs = scbp ^ ((row >> 1) & 3);
            gload16(Ahi + (size_t)(row0 + row) * HDIM + k0 + cbs * 8, &sh[buf][AHI + seg * 512]);
            gload16(Alo + (size_t)(row0 + row) * HDIM + k0 + cbs * 8, &sh[buf][ALO + seg * 512]);
            gload16(Bhi + (size_t)(col0 + row) * HDIM + k0 + cbs * 8, &sh[buf][BHI + seg * 512]);
            gload16(Blo + (size_t)(col0 + row) * HDIM + k0 + cbs * 8, &sh[buf][BLO + seg * 512]);
        }
    };
    auto compute = [&](int buf) {
        bf16x8 ah[4], al[4], bh[4], bl[4];
#pragma unroll
        for (int m = 0; m < 4; m++) {
            const int r = fr_a[m];
            const int cbs = cb ^ ((r >> 1) & 3);
            ah[m] = *reinterpret_cast<const bf16x8*>(&sh[buf][AHI + r * 32 + cbs * 8]);
            al[m] = *reinterpret_cast<const bf16x8*>(&sh[buf][ALO + r * 32 + cbs * 8]);
        }
#pragma unroll
        for (int n = 0; n < 4; n++) {
            const int r = fr_b[n];
            const int cbs = cb ^ ((r >> 1) & 3);
            bh[n] = *reinterpret_cast<const bf16x8*>(&sh[buf][BHI + r * 32 + cbs * 8]);
            bl[n] = *reinterpret_cast<const bf16x8*>(&sh[buf][BLO + r * 32 + cbs * 8]);
        }
#pragma unroll
        for (int m = 0; m < 4; m++)
#pragma unroll
            for (int n = 0; n < 4; n++) {
                acc[m][n] = __builtin_amdgcn_mfma_f32_16x16x32_bf16(ah[m], bh[n], acc[m][n], 0, 0, 0);
                acc[m][n] = __builtin_amdgcn_mfma_f32_16x16x32_bf16(ah[m], bl[n], acc[m][n], 0, 0, 0);
                acc[m][n] = __builtin_amdgcn_mfma_f32_16x16x32_bf16(al[m], bh[n], acc[m][n], 0, 0, 0);
            }
    };

    stage(0, 0);
    __syncthreads();           // buf0 ready (compiler drains vmcnt before barrier)
    int cur = 0;
    for (int t = 0; t < 31; t++) {
        stage(cur ^ 1, (t + 1) * 32);   // issue next tile first
        compute(cur);                   // MFMA hides the staging latency
        __syncthreads();                // next buf ready; prev reads done
        cur ^= 1;
    }
    compute(cur);              // last K-step, no barrier needed

    const int lcol = l & 15, lrow = (l >> 4) * 4;
#pragma unroll
    for (int n = 0; n < 4; n++) {
        const int colg = col0 + wc * 64 + n * 16 + lcol;
#pragma unroll
        for (int m = 0; m < 4; m++) {
            const int rowg = row0 + wr * 64 + m * 16 + lrow;
#pragma unroll
            for (int v = 0; v < 4; v++)
                C[(size_t)(rowg + v) * HDIM + colg] = acc[m][n][v];
        }
    }
}

// ---------------------------------------------------------------------------
// MFMA band kernel (verified round 8): block = 16 q-rows, 4 waves split K.
// ---------------------------------------------------------------------------
__global__ __launch_bounds__(256) void band_mfma(const float* __restrict__ q,
                                                 const float* __restrict__ t,
                                                 const float* __restrict__ beta,
                                                 float* __restrict__ band) {
    __shared__ float lds_c[4][16][33];
    const int tid = threadIdx.x;
    const int w = tid >> 6, l = tid & 63;
    const int r0 = blockIdx.x * 16;
    const int b = r0 >> 11;
    const int i0 = r0 & (LSEQ - 1);
    const int fr = l & 15;
    const int kb = (l >> 4) * 8;

    const float* qrow = q + (size_t)(r0 + fr) * HDIM;
    const float* tbase = t + (size_t)b * LSEQ * HDIM;

    const int j0 = i0 - 4 + fr;
    const int j1 = i0 + 12 + fr;
    const int j0c = min(max(j0, 0), LSEQ - 1);
    const int j1c = min(max(j1, 0), LSEQ - 1);
    const bool v0 = (j0 >= 0) && (j0 < LSEQ);
    const bool v1 = (j1 >= 0) && (j1 < LSEQ);
    const bool interior = (i0 >= 4) && (i0 + 19 < LSEQ);
    const float4 fz = {0.f, 0.f, 0.f, 0.f};

    f32x4 c0 = {0.f, 0.f, 0.f, 0.f};
    f32x4 c1 = {0.f, 0.f, 0.f, 0.f};

#pragma unroll 2
    for (int ks = 0; ks < 8; ks++) {
        const int k0 = w * 256 + ks * 32 + kb;
        float4 qa = *reinterpret_cast<const float4*>(qrow + k0);
        float4 qb = *reinterpret_cast<const float4*>(qrow + k0 + 4);
        float4 t0a = *reinterpret_cast<const float4*>(tbase + (size_t)j0c * HDIM + k0);
        float4 t0b = *reinterpret_cast<const float4*>(tbase + (size_t)j0c * HDIM + k0 + 4);
        float4 t1a = *reinterpret_cast<const float4*>(tbase + (size_t)j1c * HDIM + k0);
        float4 t1b = *reinterpret_cast<const float4*>(tbase + (size_t)j1c * HDIM + k0 + 4);
        if (!interior) {
            if (!v0) { t0a = fz; t0b = fz; }
            if (!v1) { t1a = fz; t1b = fz; }
        }
        bf16x8 ah, al, b0h, b0l, b1h, b1l;
        split8(qa, qb, ah, al);
        split8(t0a, t0b, b0h, b0l);
        split8(t1a, t1b, b1h, b1l);
        c0 = __builtin_amdgcn_mfma_f32_16x16x32_bf16(ah, b0h, c0, 0, 0, 0);
        c0 = __builtin_amdgcn_mfma_f32_16x16x32_bf16(ah, b0l, c0, 0, 0, 0);
        c0 = __builtin_amdgcn_mfma_f32_16x16x32_bf16(al, b0h, c0, 0, 0, 0);
        c1 = __builtin_amdgcn_mfma_f32_16x16x32_bf16(ah, b1h, c1, 0, 0, 0);
        c1 = __builtin_amdgcn_mfma_f32_16x16x32_bf16(ah, b1l, c1, 0, 0, 0);
        c1 = __builtin_amdgcn_mfma_f32_16x16x32_bf16(al, b1h, c1, 0, 0, 0);
    }

#pragma unroll
    for (int v = 0; v < 4; v++) {
        lds_c[w][(l >> 4) * 4 + v][fr] = c0[v];
        lds_c[w][(l >> 4) * 4 + v][16 + fr] = c1[v];
    }
    __syncthreads();

#pragma unroll
    for (int e = tid; e < 512; e += 256) {
        const int rr = e >> 5, cc = e & 31;
        lds_c[0][rr][cc] = lds_c[0][rr][cc] + lds_c[1][rr][cc] +
                           lds_c[2][rr][cc] + lds_c[3][rr][cc];
    }
    __syncthreads();

    if (tid < 16) {
        const int il = i0 + tid;
        const int ig = r0 + tid;
        float lg[NBAND];
#pragma unroll
        for (int d = 0; d < NBAND; d++) {
            const int j = il + d - 4;
            lg[d] = (j >= 0 && j < LSEQ)
                    ? lds_c[0][tid][tid + d] + beta[(size_t)b * LSEQ + j]
                    : -1e30f;
        }
        float m = -1e30f;
#pragma unroll
        for (int d = 0; d < NBAND; d++) m = fmaxf(m, lg[d]);
        float p[NBAND], s = 0.f;
#pragma unroll
        for (int d = 0; d < NBAND; d++) { p[d] = expf(lg[d] - m); s += p[d]; }
        const float inv = 1.f / s;
#pragma unroll
        for (int d = 0; d < NBAND; d++) band[(size_t)ig * NBAND + d] = p[d] * inv;
    }
}

// ---------------------------------------------------------------------------
// Expand band probs into dense [B, L, L] output.
// ---------------------------------------------------------------------------
__global__ __launch_bounds__(256) void expand_band(const float* __restrict__ band,
                                                   float* __restrict__ out) {
    const size_t idx4 = (size_t)blockIdx.x * 256 + threadIdx.x;
    const size_t flat = idx4 * 4;
    const int j0 = (int)(flat & (LSEQ - 1));
    const size_t row = flat >> 11;
    const int i = (int)(row & (LSEQ - 1));
    float v[4];
#pragma unroll
    for (int s = 0; s < 4; s++) {
        const int dj = (j0 + s) - i + 4;
        v[s] = (dj >= 0 && dj < NBAND) ? band[row * NBAND + dj] : 0.f;
    }
    float4 o = {v[0], v[1], v[2], v[3]};
    *reinterpret_cast<float4*>(&out[flat]) = o;
}

// ---------------------------------------------------------------------------
// Fallback fp32 path (ws too small).
// ---------------------------------------------------------------------------
__global__ __launch_bounds__(256) void gemm_nt_bias(const float* __restrict__ A,
                                                    const float* __restrict__ B,
                                                    const float* __restrict__ bias,
                                                    float* __restrict__ C) {
    __shared__ float As[8][132];
    __shared__ float Bs[8][132];
    const int tid = threadIdx.x;
    const int row0 = blockIdx.x * 128, col0 = blockIdx.y * 128;
    const int lr = tid >> 1, lc = (tid & 1) * 4;
    const int tx = tid & 15, ty = tid >> 4;
    float acc[2][2][4][4];
#pragma unroll
    for (int a = 0; a < 2; a++)
#pragma unroll
        for (int b = 0; b < 2; b++)
#pragma unroll
            for (int c = 0; c < 4; c++)
#pragma unroll
                for (int d = 0; d < 4; d++) acc[a][b][c][d] = 0.f;
    for (int k0 = 0; k0 < HDIM; k0 += 8) {
        float4 av = *reinterpret_cast<const float4*>(&A[(size_t)(row0 + lr) * HDIM + k0 + lc]);
        float4 bv = *reinterpret_cast<const float4*>(&B[(size_t)(col0 + lr) * HDIM + k0 + lc]);
        __syncthreads();
        As[lc + 0][lr] = av.x; As[lc + 1][lr] = av.y; As[lc + 2][lr] = av.z; As[lc + 3][lr] = av.w;
        Bs[lc + 0][lr] = bv.x; Bs[lc + 1][lr] = bv.y; Bs[lc + 2][lr] = bv.z; Bs[lc + 3][lr] = bv.w;
        __syncthreads();
#pragma unroll
        for (int kk = 0; kk < 8; kk++) {
            float4 a0 = *reinterpret_cast<const float4*>(&As[kk][ty * 4]);
            float4 a1 = *reinterpret_cast<const float4*>(&As[kk][64 + ty * 4]);
            float4 b0 = *reinterpret_cast<const float4*>(&Bs[kk][tx * 4]);
            float4 b1 = *reinterpret_cast<const float4*>(&Bs[kk][64 + tx * 4]);
            float am[2][4] = {{a0.x, a0.y, a0.z, a0.w}, {a1.x, a1.y, a1.z, a1.w}};
            float bw[2][4] = {{b0.x, b0.y, b0.z, b0.w}, {b1.x, b1.y, b1.z, b1.w}};
#pragma unroll
            for (int mi = 0; mi < 2; mi++)
#pragma unroll
                for (int ni = 0; ni < 2; ni++)
#pragma unroll
                    for (int mm = 0; mm < 4; mm++)
#pragma unroll
                        for (int nn = 0; nn < 4; nn++)
                            acc[mi][ni][mm][nn] += am[mi][mm] * bw[ni][nn];
        }
    }
#pragma unroll
    for (int mi = 0; mi < 2; mi++)
#pragma unroll
        for (int mm = 0; mm < 4; mm++) {
            const int r = row0 + mi * 64 + ty * 4 + mm;
#pragma unroll
            for (int ni = 0; ni < 2; ni++) {
                const int c = col0 + ni * 64 + tx * 4;
                float4 o;
                o.x = acc[mi][ni][mm][0] + bias[c + 0];
                o.y = acc[mi][ni][mm][1] + bias[c + 1];
                o.z = acc[mi][ni][mm][2] + bias[c + 2];
                o.w = acc[mi][ni][mm][3] + bias[c + 3];
                *reinterpret_cast<float4*>(&C[(size_t)r * HDIM + c]) = o;
            }
        }
}

__global__ __launch_bounds__(256) void band_softmax(const float* __restrict__ qs,
                                                    const float* __restrict__ ks,
                                                    float* __restrict__ band) {
    const int wave = threadIdx.x >> 6;
    const int lane = threadIdx.x & 63;
    const int r = blockIdx.x * 4 + wave;
    const int b = r >> 11;
    const int i = r & (LSEQ - 1);
    const float* qrow = qs + (size_t)r * HDIM;
    const float* kbase = ks + (size_t)b * LSEQ * HDIM;
    float acc[NBAND];
#pragma unroll
    for (int d = 0; d < NBAND; d++) acc[d] = 0.f;
    for (int h = lane; h < HDIM; h += 64) {
        const float qv = qrow[h];
#pragma unroll
        for (int d = 0; d < NBAND; d++) {
            const int j = i + d - 4;
            if (j >= 0 && j < LSEQ)
                acc[d] += qv * kbase[(size_t)j * HDIM + h];
        }
    }
#pragma unroll
    for (int d = 0; d < NBAND; d++) {
        float v = acc[d];
#pragma unroll
        for (int off = 32; off > 0; off >>= 1) v += __shfl_xor(v, off, 64);
        acc[d] = v;
    }
    if (lane == 0) {
        float m = -1e30f;
#pragma unroll
        for (int d = 0; d < NBAND; d++) {
            const int j = i + d - 4;
            if (j >= 0 && j < LSEQ) m = fmaxf(m, acc[d]);
        }
        float p[NBAND];
        float s = 0.f;
#pragma unroll
        for (int d = 0; d < NBAND; d++) {
            const int j = i + d - 4;
            p[d] = (j >= 0 && j < LSEQ) ? expf(acc[d] - m) : 0.f;
            s += p[d];
        }
        const float inv = 1.f / s;
#pragma unroll
        for (int d = 0; d < NBAND; d++) band[(size_t)r * NBAND + d] = p[d] * inv;
    }
}

extern "C" void kernel_launch(void* const* d_in, const int* in_sizes, int n_in,
                              void* d_out, int out_size, void* d_ws, size_t ws_size,
                              hipStream_t stream) {
    const float* q  = (const float*)d_in[0];
    const float* k  = (const float*)d_in[1];
    const float* Wq = (const float*)d_in[2];
    const float* bq = (const float*)d_in[3];
    const float* Wk = (const float*)d_in[4];
    const float* bk = (const float*)d_in[5];
    float* out = (float*)d_out;

    // ---- workspace layout (~36.6 MB, proven available) ----
    const size_t bandB = (size_t)ROWS * NBAND * sizeof(float);
    char* p = (char*)d_ws;
    float* band = (float*)p;                 p += bandB;
    unsigned short* Xhi = (unsigned short*)p; p += (size_t)ROWS * HDIM * 2;   // 16 MB
    unsigned short* Xlo = (unsigned short*)p; p += (size_t)ROWS * HDIM * 2;   // 16 MB
    unsigned short* Mhi = (unsigned short*)p; p += (size_t)HDIM * HDIM * 2;   // 2 MB
    unsigned short* Mlo = (unsigned short*)p; p += (size_t)HDIM * HDIM * 2;   // 2 MB
    float* w        = (float*)p;             p += HDIM * sizeof(float);
    float* wpart    = (float*)p;             p += 64 * HDIM * sizeof(float);
    float* beta     = (float*)p;             p += ROWS * sizeof(float);
    const size_t need = (size_t)(p - (char*)d_ws);

    // WqT/WkT bf16 splits live in the (not-yet-written) Xhi region
    unsigned short* WqTh = Xhi;
    unsigned short* WqTl = Xhi + (size_t)HDIM * HDIM;
    unsigned short* WkTh = Xhi + 2 * (size_t)HDIM * HDIM;
    unsigned short* WkTl = Xhi + 3 * (size_t)HDIM * HDIM;

    // d_out scratch: t at [0, 8.4M floats); Mparts at [8.4M, 12.6M) (4 parts)
    float* t = out;
    float* Mparts = out + (size_t)ROWS * HDIM;

    if (ws_size >= need) {
        wpart_kernel<<<64, 256, 0, stream>>>(Wk, bq, wpart);
        wreduce<<<4, 256, 0, stream>>>(wpart, w);
        dim3 tg(16, 16, 2);
        transpose_convert<<<tg, 256, 0, stream>>>(Wq, Wk, WqTh, WqTl, WkTh, WkTl);
        dim3 mg(8, 8, 4);
        gemm_part<<<mg, 256, 0, stream>>>(WqTh, WqTl, WkTh, WkTl, Mparts);
        reduceM_convert<<<HDIM * HDIM / 4 / 256, 256, 0, stream>>>(Mparts, Mhi, Mlo);
        convert_k_beta<<<ROWS, 256, 0, stream>>>(k, w, Xhi, Xlo, beta);
        dim3 gg(ROWS / 128, HDIM / 128);
        gemm_t<<<gg, 256, 0, stream>>>(Xhi, Xlo, Mhi, Mlo, t);
        band_mfma<<<ROWS / 16, 256, 0, stream>>>(q, t, beta, band);
        expand_band<<<(size_t)ROWS * LSEQ / 4 / 256, 256, 0, stream>>>(band, out);
    } else {
        float* qs = out;
        float* ks = out + (size_t)ROWS * HDIM;
        dim3 gg(ROWS / 128, HDIM / 128);
        gemm_nt_bias<<<gg, 256, 0, stream>>>(q, Wq, bq, qs);
        gemm_nt_bias<<<gg, 256, 0, stream>>>(k, Wk, bk, ks);
        band_softmax<<<ROWS / 4, 256, 0, stream>>>(qs, ks, band);
        expand_band<<<(size_t)ROWS * LSEQ / 4 / 256, 256, 0, stream>>>(band, out);
    }
}